// Round 7
// baseline (357.859 us; speedup 1.0000x reference)
//
#include <hip/hip_runtime.h>
#include <math.h>

// B=4, H=W=64, C=256, DG=8, K=3, cpg=32; coarse: [4,32,32,256]

typedef __attribute__((ext_vector_type(8))) short bf16x8;
typedef __attribute__((ext_vector_type(4))) short bf16x4;
typedef __attribute__((ext_vector_type(4))) float f32x4;
#define MFMA16(a,b,c) __builtin_amdgcn_mfma_f32_16x16x32_bf16(a,b,c,0,0,0)

__device__ inline short f2b(float x){
  union { float f; unsigned u; } v; v.f = x;
  unsigned r = v.u + 0x7FFFu + ((v.u >> 16) & 1u);
  return (short)(r >> 16);
}

// workspace layout (float offsets)
#define OFS_MEAN  0u
#define OFS_GATE  1024u
#define OFS_CUP   264192u
#define OFS_FCAL  4458496u
#define OFS_ALGB  8652800u     // bf16 [16384][512]
#define OFS_OM    12847104u    // f32  [16384][216]
#define OFS_DWB   16386048u    // bf16 frag [72][16][64][8]
#define OFS_OMWB  16680960u    // bf16 frag [144][16][64][8]
#define OFS_WBB   17270784u    // bf16 frag [4][8][16][64][8]
#define OFS_OWB   17401856u    // bf16 frag [16][32][64][8]

__global__ void k_zero(float* __restrict__ p){
  p[blockIdx.x*256 + threadIdx.x] = 0.f;
}

// GAP: 256 blocks (b*64+chunk), float4 loads, LDS reduce, 1 atomic/ch
__global__ __launch_bounds__(256) void k_gap(const float* __restrict__ fine,
                                             float* __restrict__ mean){
  __shared__ float red[4*256];
  int b = blockIdx.x >> 6, chunk = blockIdx.x & 63;
  int c4 = threadIdx.x & 63, rl = threadIdx.x >> 6;
  const float4* F4 = (const float4*)fine;
  float4 s = {0.f,0.f,0.f,0.f};
  for (int it = 0; it < 16; ++it){
    int row = chunk*64 + it*4 + rl;
    float4 v = F4[((size_t)(b*4096 + row))*64 + c4];
    s.x += v.x; s.y += v.y; s.z += v.z; s.w += v.w;
  }
  *(float4*)&red[rl*256 + c4*4] = s;
  __syncthreads();
  int c = threadIdx.x;
  float t = red[c] + red[256+c] + red[512+c] + red[768+c];
  atomicAdd(&mean[b*256 + c], t);
}

__global__ void k_attn(const float* __restrict__ mean, const float* __restrict__ aw,
                       float* __restrict__ gate){
  __shared__ float m[256];
  int b = blockIdx.x, f = threadIdx.x;
  m[f] = mean[b*256 + f] * (1.f/4096.f);
  __syncthreads();
  float s = 0.f;
  for (int c = 0; c < 256; ++c) s += m[c] * aw[c*256 + f];
  gate[b*256 + f] = 1.f + 1.f/(1.f + expf(-s));
}

// Wb frags: wbb[((b*8+ksg)*16+nt)*64+l][8]; w = gate[b,k]*sw[k,n]
__global__ void k_foldw_frag(const float* __restrict__ gate, const float* __restrict__ sw,
                             short* __restrict__ wbb){
  int t = blockIdx.x*256 + threadIdx.x;          // 32768
  int l = t & 63, nt = (t >> 6) & 15, ksg = (t >> 10) & 7, b = t >> 13;
  int n = nt*16 + (l & 15);
  int kb = ksg*32 + (l >> 4)*8;
  bf16x8 o;
#pragma unroll
  for (int j = 0; j < 8; ++j){
    int k = kb + j;
    o[j] = f2b(gate[b*256 + k] * sw[(size_t)k*256 + n]);
  }
  ((bf16x8*)wbb)[t] = o;
}

// offset_w frags, 2x folded for k>=256: owb[(ksg*32+nt)*64+l][8]
__global__ void k_cvt_owb(const float* __restrict__ ow, short* __restrict__ owb){
  int t = blockIdx.x*256 + threadIdx.x;          // 32768
  int l = t & 63, nt = (t >> 6) & 31, ksg = t >> 11;
  int n = nt*16 + (l & 15);
  int kb = ksg*32 + (l >> 4)*8;
  float sc = (kb >= 256) ? 2.f : 1.f;
  bf16x8 o;
#pragma unroll
  for (int j = 0; j < 8; ++j) o[j] = f2b(sc * ow[(size_t)(kb + j)*512 + n]);
  ((bf16x8*)owb)[t] = o;
}

__global__ void k_up(const float* __restrict__ coarse, float* __restrict__ cup){
  int idx = blockIdx.x*256 + threadIdx.x;
  int c4 = idx & 63, x = (idx >> 6) & 63, y = (idx >> 12) & 63, b = idx >> 18;
  float fy = 0.5f*y - 0.25f, fx = 0.5f*x - 0.25f;
  float yf = floorf(fy), xf = floorf(fx);
  float wy = fy - yf, wx = fx - xf;
  int r0 = max(0, min(31, (int)yf)), r1 = max(0, min(31, (int)yf + 1));
  int c0 = max(0, min(31, (int)xf)), c1 = max(0, min(31, (int)xf + 1));
  const float4* src = (const float4*)coarse;
  float4 v00 = src[((b*32 + r0)*32 + c0)*64 + c4];
  float4 v01 = src[((b*32 + r0)*32 + c1)*64 + c4];
  float4 v10 = src[((b*32 + r1)*32 + c0)*64 + c4];
  float4 v11 = src[((b*32 + r1)*32 + c1)*64 + c4];
  float w00 = (1.f-wy)*(1.f-wx), w01 = (1.f-wy)*wx, w10 = wy*(1.f-wx), w11 = wy*wx;
  float4 o;
  o.x = v00.x*w00 + v01.x*w01 + v10.x*w10 + v11.x*w11;
  o.y = v00.y*w00 + v01.y*w01 + v10.y*w10 + v11.y*w11;
  o.z = v00.z*w00 + v01.z*w01 + v10.z*w10 + v11.z*w11;
  o.w = v00.w*w00 + v01.w*w01 + v10.w*w10 + v11.w*w11;
  ((float4*)cup)[idx] = o;
}

// fine_cal = fine @ Wb[b] via MFMA; M-tile 32, stage fine->bf16 LDS
#define FST 264
__global__ __launch_bounds__(256) void k_fcal(const float* __restrict__ fine,
                                              const short* __restrict__ wbb,
                                              float* __restrict__ fcal){
  __shared__ short ab[32*FST];
  int m0 = blockIdx.x*32, b = m0 >> 12;
  int tid = threadIdx.x, lane = tid & 63, wave = tid >> 6;
  int arow = lane & 15, aquad = lane >> 4;
  const float4* F4 = (const float4*)(fine + (size_t)m0*256);
  for (int it = 0; it < 8; ++it){
    int idx = it*256 + tid;                      // 0..2047
    int row = idx >> 6, c4 = idx & 63;
    float4 v = F4[row*64 + c4];
    bf16x4 s4 = { f2b(v.x), f2b(v.y), f2b(v.z), f2b(v.w) };
    *(bf16x4*)&ab[row*FST + c4*4] = s4;
  }
  __syncthreads();
  f32x4 acc[2][4];
#pragma unroll
  for (int s = 0; s < 2; ++s)
#pragma unroll
    for (int t = 0; t < 4; ++t) acc[s][t] = (f32x4){0.f,0.f,0.f,0.f};
  const bf16x8* W8 = (const bf16x8*)wbb;
  for (int ks = 0; ks < 8; ++ks){
    bf16x8 a0 = *(const bf16x8*)&ab[arow*FST + ks*32 + aquad*8];
    bf16x8 a1 = *(const bf16x8*)&ab[(16 + arow)*FST + ks*32 + aquad*8];
    const bf16x8* wp = W8 + ((size_t)((b*8 + ks)*16 + wave*4))*64 + lane;
#pragma unroll
    for (int t = 0; t < 4; ++t){
      bf16x8 bw = wp[t*64];
      acc[0][t] = MFMA16(a0, bw, acc[0][t]);
      acc[1][t] = MFMA16(a1, bw, acc[1][t]);
    }
  }
#pragma unroll
  for (int t = 0; t < 4; ++t){
    int f = wave*64 + t*16 + (lane & 15);
#pragma unroll
    for (int s = 0; s < 2; ++s)
#pragma unroll
      for (int r = 0; r < 4; ++r){
        int m = m0 + s*16 + aquad*4 + r;
        fcal[(size_t)m*256 + f] = acc[s][t][r];
      }
  }
}

// align = concat(fcal, cup) @ owb (2x folded) via MFMA; inline fp32->bf16 A-frags
__global__ __launch_bounds__(256) void k_align(const float* __restrict__ fcal,
                                               const float* __restrict__ cup,
                                               const short* __restrict__ owb,
                                               short* __restrict__ algb){
  int m0 = blockIdx.x*32;
  int tid = threadIdx.x, lane = tid & 63, wave = tid >> 6;
  int arow = lane & 15, aquad = lane >> 4;
  f32x4 acc[2][8];
#pragma unroll
  for (int s = 0; s < 2; ++s)
#pragma unroll
    for (int t = 0; t < 8; ++t) acc[s][t] = (f32x4){0.f,0.f,0.f,0.f};
  const bf16x8* OW8 = (const bf16x8*)owb;
  for (int ks = 0; ks < 16; ++ks){
    const float* src = (ks < 8) ? fcal : cup;
    int ko = (ks & 7)*32 + aquad*8;
    const float4* ap0 = (const float4*)(src + (size_t)(m0 + arow)*256 + ko);
    const float4* ap1 = (const float4*)(src + (size_t)(m0 + 16 + arow)*256 + ko);
    float4 f00 = ap0[0], f01 = ap0[1];
    float4 f10 = ap1[0], f11 = ap1[1];
    bf16x8 a0 = { f2b(f00.x), f2b(f00.y), f2b(f00.z), f2b(f00.w),
                  f2b(f01.x), f2b(f01.y), f2b(f01.z), f2b(f01.w) };
    bf16x8 a1 = { f2b(f10.x), f2b(f10.y), f2b(f10.z), f2b(f10.w),
                  f2b(f11.x), f2b(f11.y), f2b(f11.z), f2b(f11.w) };
    const bf16x8* wp = OW8 + ((size_t)(ks*32 + wave*8))*64 + lane;
#pragma unroll
    for (int t = 0; t < 8; ++t){
      bf16x8 bw = wp[t*64];
      acc[0][t] = MFMA16(a0, bw, acc[0][t]);
      acc[1][t] = MFMA16(a1, bw, acc[1][t]);
    }
  }
#pragma unroll
  for (int t = 0; t < 8; ++t){
    int n = wave*128 + t*16 + (lane & 15);
#pragma unroll
    for (int s = 0; s < 2; ++s)
#pragma unroll
      for (int r = 0; r < 4; ++r){
        int m = m0 + s*16 + aquad*4 + r;
        algb[(size_t)m*512 + n] = f2b(acc[s][t][r]);
      }
  }
}

// dcn_w -> B-frag bf16
__global__ void k_cvt_dwb(const float* __restrict__ dw, short* __restrict__ dwb){
  int t = blockIdx.x*256 + threadIdx.x;          // 73728
  int l = t & 63, nt = (t >> 6) & 15, ksg = t >> 10;
  int n = nt*16 + (l & 15);
  int kb = ksg*32 + (l >> 4)*8;
  bf16x8 o;
#pragma unroll
  for (int j = 0; j < 8; ++j) o[j] = f2b(dw[(size_t)(kb + j)*256 + n]);
  ((bf16x8*)dwb)[t] = o;
}

// om_w -> B-frag bf16, N padded 216->256
__global__ void k_cvt_omwb(const float* __restrict__ omw, short* __restrict__ omwb){
  int t = blockIdx.x*256 + threadIdx.x;          // 147456
  int l = t & 63, nt = (t >> 6) & 15, ksg = t >> 10;
  int n = nt*16 + (l & 15);
  int kb = ksg*32 + (l >> 4)*8;
  bf16x8 o;
#pragma unroll
  for (int j = 0; j < 8; ++j)
    o[j] = (n < 216) ? f2b(omw[(size_t)(kb + j)*216 + n]) : (short)0;
  ((bf16x8*)omwb)[t] = o;
}

// om conv3x3 as MFMA implicit GEMM. M-tile 32, N padded 256, phase per ky.
#define XST 520
__global__ __launch_bounds__(256) void k_om(const short* __restrict__ algb,
                                            const short* __restrict__ omwb,
                                            const float* __restrict__ omb,
                                            float* __restrict__ om){
  __shared__ short xbuf[34*XST];
  int m0 = blockIdx.x*32;
  int b = m0 >> 12, y = (m0 & 4095) >> 6, x0 = m0 & 63;
  int tid = threadIdx.x;
  int lane = tid & 63, wave = tid >> 6;
  int arow = lane & 15, aquad = lane >> 4;
  f32x4 acc[2][4];
#pragma unroll
  for (int s = 0; s < 2; ++s)
#pragma unroll
    for (int t = 0; t < 4; ++t) acc[s][t] = (f32x4){0.f,0.f,0.f,0.f};
  const bf16x8* W8 = (const bf16x8*)omwb;
  for (int ky = 0; ky < 3; ++ky){
    int yy = y + ky - 1;
    if ((unsigned)yy >= 64u) continue;           // block-uniform
    __syncthreads();
    const short* srow = algb + (size_t)((b*64 + yy)*64)*512;
    for (int it = 0; it < 9; ++it){
      int idx = it*256 + tid;
      if (idx < 2176){
        int xx = idx >> 6, l8 = idx & 63;
        int gx = x0 - 1 + xx;
        bf16x8 v = (bf16x8){0,0,0,0,0,0,0,0};
        if ((unsigned)gx < 64u) v = *(const bf16x8*)(srow + (size_t)gx*512 + l8*8);
        *(bf16x8*)&xbuf[xx*XST + l8*8] = v;
      }
    }
    __syncthreads();
    for (int ks = 0; ks < 48; ++ks){
      int kl = ks*32 + aquad*8;
      int kx = kl >> 9, cc = kl & 511;
      bf16x8 a0 = *(const bf16x8*)&xbuf[(arow + kx)*XST + cc];
      bf16x8 a1 = *(const bf16x8*)&xbuf[(16 + arow + kx)*XST + cc];
      const bf16x8* wp = W8 + ((size_t)((ky*48 + ks)*16 + wave*4))*64 + lane;
#pragma unroll
      for (int t = 0; t < 4; ++t){
        bf16x8 bw = wp[t*64];
        acc[0][t] = MFMA16(a0, bw, acc[0][t]);
        acc[1][t] = MFMA16(a1, bw, acc[1][t]);
      }
    }
  }
#pragma unroll
  for (int t = 0; t < 4; ++t){
    int f = wave*64 + t*16 + (lane & 15);
    if (f < 216){
      float bias = omb[f];
#pragma unroll
      for (int s = 0; s < 2; ++s)
#pragma unroll
        for (int r = 0; r < 4; ++r){
          int m = m0 + s*16 + (lane >> 4)*4 + r;
          om[(size_t)m*216 + f] = acc[s][t][r] + bias;
        }
    }
  }
}

// DCNv2: per-LANE sample staging (params once/sample, 32-ch gather per lane),
// then MFMA GEMM. M-tile 16. Same math as r6, just transposed work division.
#define VST 776
__global__ __launch_bounds__(256) void k_dcn(const float* __restrict__ cup,
                                             const float* __restrict__ om,
                                             const short* __restrict__ dwb,
                                             const float* __restrict__ db,
                                             const float* __restrict__ fcal,
                                             float* __restrict__ out){
  __shared__ short valb[16*VST];   // 24832 B
  int m0 = blockIdx.x*16;
  int b = m0 >> 12, y = (m0 & 4095) >> 6, x0 = m0 & 63;
  int tid = threadIdx.x;
  int lane = tid & 63, wave = tid >> 6;
  int arow = lane & 15, aquad = lane >> 4;
  f32x4 acc[4];
#pragma unroll
  for (int t = 0; t < 4; ++t) acc[t] = (f32x4){0.f,0.f,0.f,0.f};
  const float4* cb4 = (const float4*)(cup + (size_t)b*4096*256);
  const bf16x8* W8 = (const bf16x8*)dwb;

  for (int ph = 0; ph < 3; ++ph){
    __syncthreads();
    // 384 samples (16 rows x 8 g x 3 taps); one sample per lane, 2 passes
    for (int pass = 0; pass < 2; ++pass){
      int s = pass*256 + tid;
      if (s < 384){
        int i = s / 24, r = s - i*24, g = r / 3, kk = r - g*3;
        const float* omp = om + (size_t)(m0 + i)*216;
        int k = ph*3 + kk;
        float dy = omp[(g*9 + k)*2 + 0];
        float dx = omp[(g*9 + k)*2 + 1];
        float mv = 1.f / (1.f + expf(-omp[144 + g*9 + k]));
        float yp = (float)(y + ph - 1) + dy;
        float xp = (float)(x0 + i + kk - 1) + dx;
        float yf = floorf(yp), xf = floorf(xp);
        float wy = yp - yf, wx = xp - xf;
        int iy = (int)yf, ix = (int)xf;
        float wA = (1.f-wy)*(1.f-wx), wB = (1.f-wy)*wx, wC = wy*(1.f-wx), wD = wy*wx;
        bool y0ok = (unsigned)iy < 64u, y1ok = (unsigned)(iy+1) < 64u;
        bool x0ok = (unsigned)ix < 64u, x1ok = (unsigned)(ix+1) < 64u;
        if (!(y0ok && x0ok)) wA = 0.f;
        if (!(y0ok && x1ok)) wB = 0.f;
        if (!(y1ok && x0ok)) wC = 0.f;
        if (!(y1ok && x1ok)) wD = 0.f;
        int y0c = min(max(iy, 0), 63), y1c = min(max(iy + 1, 0), 63);
        int x0c = min(max(ix, 0), 63), x1c = min(max(ix + 1, 0), 63);
        const float4* p00 = cb4 + (y0c*64 + x0c)*64 + g*8;
        const float4* p01 = cb4 + (y0c*64 + x1c)*64 + g*8;
        const float4* p10 = cb4 + (y1c*64 + x0c)*64 + g*8;
        const float4* p11 = cb4 + (y1c*64 + x1c)*64 + g*8;
        int col = i*VST + kk*256 + g*32;
#pragma unroll
        for (int c4 = 0; c4 < 8; ++c4){
          float4 l00 = p00[c4], l01 = p01[c4], l10 = p10[c4], l11 = p11[c4];
          bf16x4 o = { f2b((wA*l00.x + wB*l01.x + wC*l10.x + wD*l11.x) * mv),
                       f2b((wA*l00.y + wB*l01.y + wC*l10.y + wD*l11.y) * mv),
                       f2b((wA*l00.z + wB*l01.z + wC*l10.z + wD*l11.z) * mv),
                       f2b((wA*l00.w + wB*l01.w + wC*l10.w + wD*l11.w) * mv) };
          *(bf16x4*)&valb[col + c4*4] = o;
        }
      }
    }
    __syncthreads();
    for (int ks = 0; ks < 24; ++ks){
      bf16x8 a = *(const bf16x8*)&valb[arow*VST + ks*32 + aquad*8];
      const bf16x8* wp = W8 + ((size_t)((ph*24 + ks)*16 + wave*4))*64 + lane;
#pragma unroll
      for (int t = 0; t < 4; ++t)
        acc[t] = MFMA16(a, wp[t*64], acc[t]);
    }
  }
#pragma unroll
  for (int t = 0; t < 4; ++t){
    int f = wave*64 + t*16 + (lane & 15);
    float bias = db[f];
#pragma unroll
    for (int r = 0; r < 4; ++r){
      int m = m0 + aquad*4 + r;
      out[(size_t)m*256 + f] = fmaxf(acc[t][r] + bias, 0.f) + fcal[(size_t)m*256 + f];
    }
  }
}

extern "C" void kernel_launch(void* const* d_in, const int* in_sizes, int n_in,
                              void* d_out, int out_size, void* d_ws, size_t ws_size,
                              hipStream_t stream){
  const float* fine     = (const float*)d_in[0];
  const float* coarse   = (const float*)d_in[1];
  const float* attend_w = (const float*)d_in[2];
  const float* select_w = (const float*)d_in[3];
  const float* offset_w = (const float*)d_in[4];
  const float* om_w     = (const float*)d_in[5];
  const float* om_b     = (const float*)d_in[6];
  const float* dcn_w    = (const float*)d_in[7];
  const float* dcn_b    = (const float*)d_in[8];
  float* out = (float*)d_out;
  float* ws  = (float*)d_ws;

  float* mean = ws + OFS_MEAN;
  float* gate = ws + OFS_GATE;
  float* cup  = ws + OFS_CUP;
  float* fcal = ws + OFS_FCAL;
  short* algb = (short*)(ws + OFS_ALGB);
  float* om   = ws + OFS_OM;
  short* dwb  = (short*)(ws + OFS_DWB);
  short* omwb = (short*)(ws + OFS_OMWB);
  short* wbb  = (short*)(ws + OFS_WBB);
  short* owb  = (short*)(ws + OFS_OWB);

  hipLaunchKernelGGL(k_zero,       dim3(4),    dim3(256), 0, stream, mean);
  hipLaunchKernelGGL(k_cvt_dwb,    dim3(288),  dim3(256), 0, stream, dcn_w, dwb);
  hipLaunchKernelGGL(k_cvt_omwb,   dim3(576),  dim3(256), 0, stream, om_w, omwb);
  hipLaunchKernelGGL(k_cvt_owb,    dim3(128),  dim3(256), 0, stream, offset_w, owb);
  hipLaunchKernelGGL(k_gap,        dim3(256),  dim3(256), 0, stream, fine, mean);
  hipLaunchKernelGGL(k_attn,       dim3(4),    dim3(256), 0, stream, mean, attend_w, gate);
  hipLaunchKernelGGL(k_foldw_frag, dim3(128),  dim3(256), 0, stream, gate, select_w, wbb);
  hipLaunchKernelGGL(k_up,         dim3(4096), dim3(256), 0, stream, coarse, cup);
  hipLaunchKernelGGL(k_fcal,       dim3(512),  dim3(256), 0, stream, fine, wbb, fcal);
  hipLaunchKernelGGL(k_align,      dim3(512),  dim3(256), 0, stream, fcal, cup, owb, algb);
  hipLaunchKernelGGL(k_om,         dim3(512),  dim3(256), 0, stream, algb, omwb, om_b, om);
  hipLaunchKernelGGL(k_dcn,        dim3(1024), dim3(256), 0, stream, cup, om, dwb, dcn_b, fcal, out);
  (void)in_sizes; (void)n_in; (void)out_size; (void)ws_size;
}

// Round 8
// 352.114 us; speedup vs baseline: 1.0163x; 1.0163x over previous
//
#include <hip/hip_runtime.h>
#include <math.h>

// B=4, H=W=64, C=256, DG=8, K=3, cpg=32; coarse: [4,32,32,256]

typedef __attribute__((ext_vector_type(8))) short bf16x8;
typedef __attribute__((ext_vector_type(4))) short bf16x4;
typedef __attribute__((ext_vector_type(4))) float f32x4;
#define MFMA16(a,b,c) __builtin_amdgcn_mfma_f32_16x16x32_bf16(a,b,c,0,0,0)

__device__ inline short f2b(float x){
  union { float f; unsigned u; } v; v.f = x;
  unsigned r = v.u + 0x7FFFu + ((v.u >> 16) & 1u);
  return (short)(r >> 16);
}

// workspace layout (float offsets)
#define OFS_GATE  1024u
#define OFS_PART  2048u        // f32 [256][256] gap partials
#define OFS_CUP   264192u
#define OFS_FCAL  4458496u
#define OFS_ALGB  8652800u     // bf16 [16384][512]
#define OFS_OM    12847104u    // f32  [16384][216]
#define OFS_DWB   16386048u    // bf16 frag [72][16][64][8]
#define OFS_OMWB  16680960u    // bf16 frag [144][16][64][8]
#define OFS_WBB   17270784u    // bf16 frag [4][8][16][64][8]
#define OFS_OWB   17401856u    // bf16 frag [16][32][64][8]

// GAP partials: 256 blocks (b*64+chunk), float4 loads, LDS reduce, no atomics
__global__ __launch_bounds__(256) void k_gap(const float* __restrict__ fine,
                                             float* __restrict__ part){
  __shared__ float red[4*256];
  int b = blockIdx.x >> 6, chunk = blockIdx.x & 63;
  int c4 = threadIdx.x & 63, rl = threadIdx.x >> 6;
  const float4* F4 = (const float4*)fine;
  float4 s = {0.f,0.f,0.f,0.f};
  for (int it = 0; it < 16; ++it){
    int row = chunk*64 + it*4 + rl;
    float4 v = F4[((size_t)(b*4096 + row))*64 + c4];
    s.x += v.x; s.y += v.y; s.z += v.z; s.w += v.w;
  }
  *(float4*)&red[rl*256 + c4*4] = s;
  __syncthreads();
  int c = threadIdx.x;
  part[(size_t)blockIdx.x*256 + c] = red[c] + red[256+c] + red[512+c] + red[768+c];
}

__global__ void k_attn(const float* __restrict__ part, const float* __restrict__ aw,
                       float* __restrict__ gate){
  __shared__ float m[256];
  int b = blockIdx.x, f = threadIdx.x;
  float sm = 0.f;
  for (int ch = 0; ch < 64; ++ch) sm += part[(size_t)(b*64 + ch)*256 + f];
  m[f] = sm * (1.f/4096.f);
  __syncthreads();
  float s = 0.f;
  for (int c = 0; c < 256; ++c) s += m[c] * aw[c*256 + f];
  gate[b*256 + f] = 1.f + 1.f/(1.f + expf(-s));
}

// Wb frags: wbb[((b*8+ksg)*16+nt)*64+l][8]; w = gate[b,k]*sw[k,n]
__global__ void k_foldw_frag(const float* __restrict__ gate, const float* __restrict__ sw,
                             short* __restrict__ wbb){
  int t = blockIdx.x*256 + threadIdx.x;          // 32768
  int l = t & 63, nt = (t >> 6) & 15, ksg = (t >> 10) & 7, b = t >> 13;
  int n = nt*16 + (l & 15);
  int kb = ksg*32 + (l >> 4)*8;
  bf16x8 o;
#pragma unroll
  for (int j = 0; j < 8; ++j){
    int k = kb + j;
    o[j] = f2b(gate[b*256 + k] * sw[(size_t)k*256 + n]);
  }
  ((bf16x8*)wbb)[t] = o;
}

// fused weight converters: blocks [0,288) dwb, [288,864) omwb, [864,992) owb
__global__ void k_cvtw(const float* __restrict__ dw, const float* __restrict__ omw,
                       const float* __restrict__ ow, short* __restrict__ dwb,
                       short* __restrict__ omwb, short* __restrict__ owb){
  int blk = blockIdx.x;
  if (blk < 288){
    int t = blk*256 + threadIdx.x;               // 73728
    int l = t & 63, nt = (t >> 6) & 15, ksg = t >> 10;
    int n = nt*16 + (l & 15);
    int kb = ksg*32 + (l >> 4)*8;
    bf16x8 o;
#pragma unroll
    for (int j = 0; j < 8; ++j) o[j] = f2b(dw[(size_t)(kb + j)*256 + n]);
    ((bf16x8*)dwb)[t] = o;
  } else if (blk < 864){
    int t = (blk - 288)*256 + threadIdx.x;       // 147456
    int l = t & 63, nt = (t >> 6) & 15, ksg = t >> 10;
    int n = nt*16 + (l & 15);
    int kb = ksg*32 + (l >> 4)*8;
    bf16x8 o;
#pragma unroll
    for (int j = 0; j < 8; ++j)
      o[j] = (n < 216) ? f2b(omw[(size_t)(kb + j)*216 + n]) : (short)0;
    ((bf16x8*)omwb)[t] = o;
  } else {
    int t = (blk - 864)*256 + threadIdx.x;       // 32768
    int l = t & 63, nt = (t >> 6) & 31, ksg = t >> 11;
    int n = nt*16 + (l & 15);
    int kb = ksg*32 + (l >> 4)*8;
    float sc = (kb >= 256) ? 2.f : 1.f;
    bf16x8 o;
#pragma unroll
    for (int j = 0; j < 8; ++j) o[j] = f2b(sc * ow[(size_t)(kb + j)*512 + n]);
    ((bf16x8*)owb)[t] = o;
  }
}

__global__ void k_up(const float* __restrict__ coarse, float* __restrict__ cup){
  int idx = blockIdx.x*256 + threadIdx.x;
  int c4 = idx & 63, x = (idx >> 6) & 63, y = (idx >> 12) & 63, b = idx >> 18;
  float fy = 0.5f*y - 0.25f, fx = 0.5f*x - 0.25f;
  float yf = floorf(fy), xf = floorf(fx);
  float wy = fy - yf, wx = fx - xf;
  int r0 = max(0, min(31, (int)yf)), r1 = max(0, min(31, (int)yf + 1));
  int c0 = max(0, min(31, (int)xf)), c1 = max(0, min(31, (int)xf + 1));
  const float4* src = (const float4*)coarse;
  float4 v00 = src[((b*32 + r0)*32 + c0)*64 + c4];
  float4 v01 = src[((b*32 + r0)*32 + c1)*64 + c4];
  float4 v10 = src[((b*32 + r1)*32 + c0)*64 + c4];
  float4 v11 = src[((b*32 + r1)*32 + c1)*64 + c4];
  float w00 = (1.f-wy)*(1.f-wx), w01 = (1.f-wy)*wx, w10 = wy*(1.f-wx), w11 = wy*wx;
  float4 o;
  o.x = v00.x*w00 + v01.x*w01 + v10.x*w10 + v11.x*w11;
  o.y = v00.y*w00 + v01.y*w01 + v10.y*w10 + v11.y*w11;
  o.z = v00.z*w00 + v01.z*w01 + v10.z*w10 + v11.z*w11;
  o.w = v00.w*w00 + v01.w*w01 + v10.w*w10 + v11.w*w11;
  ((float4*)cup)[idx] = o;
}

// fine_cal = fine @ Wb[b] via MFMA; M-tile 32, stage fine->bf16 LDS
#define FST 264
__global__ __launch_bounds__(256) void k_fcal(const float* __restrict__ fine,
                                              const short* __restrict__ wbb,
                                              float* __restrict__ fcal){
  __shared__ short ab[32*FST];
  int m0 = blockIdx.x*32, b = m0 >> 12;
  int tid = threadIdx.x, lane = tid & 63, wave = tid >> 6;
  int arow = lane & 15, aquad = lane >> 4;
  const float4* F4 = (const float4*)(fine + (size_t)m0*256);
  for (int it = 0; it < 8; ++it){
    int idx = it*256 + tid;                      // 0..2047
    int row = idx >> 6, c4 = idx & 63;
    float4 v = F4[row*64 + c4];
    bf16x4 s4 = { f2b(v.x), f2b(v.y), f2b(v.z), f2b(v.w) };
    *(bf16x4*)&ab[row*FST + c4*4] = s4;
  }
  __syncthreads();
  f32x4 acc[2][4];
#pragma unroll
  for (int s = 0; s < 2; ++s)
#pragma unroll
    for (int t = 0; t < 4; ++t) acc[s][t] = (f32x4){0.f,0.f,0.f,0.f};
  const bf16x8* W8 = (const bf16x8*)wbb;
  for (int ks = 0; ks < 8; ++ks){
    bf16x8 a0 = *(const bf16x8*)&ab[arow*FST + ks*32 + aquad*8];
    bf16x8 a1 = *(const bf16x8*)&ab[(16 + arow)*FST + ks*32 + aquad*8];
    const bf16x8* wp = W8 + ((size_t)((b*8 + ks)*16 + wave*4))*64 + lane;
#pragma unroll
    for (int t = 0; t < 4; ++t){
      bf16x8 bw = wp[t*64];
      acc[0][t] = MFMA16(a0, bw, acc[0][t]);
      acc[1][t] = MFMA16(a1, bw, acc[1][t]);
    }
  }
#pragma unroll
  for (int t = 0; t < 4; ++t){
    int f = wave*64 + t*16 + (lane & 15);
#pragma unroll
    for (int s = 0; s < 2; ++s)
#pragma unroll
      for (int r = 0; r < 4; ++r){
        int m = m0 + s*16 + aquad*4 + r;
        fcal[(size_t)m*256 + f] = acc[s][t][r];
      }
  }
}

// align = concat(fcal, cup) @ owb (2x folded) via MFMA; inline fp32->bf16 A-frags
__global__ __launch_bounds__(256) void k_align(const float* __restrict__ fcal,
                                               const float* __restrict__ cup,
                                               const short* __restrict__ owb,
                                               short* __restrict__ algb){
  int m0 = blockIdx.x*32;
  int tid = threadIdx.x, lane = tid & 63, wave = tid >> 6;
  int arow = lane & 15, aquad = lane >> 4;
  f32x4 acc[2][8];
#pragma unroll
  for (int s = 0; s < 2; ++s)
#pragma unroll
    for (int t = 0; t < 8; ++t) acc[s][t] = (f32x4){0.f,0.f,0.f,0.f};
  const bf16x8* OW8 = (const bf16x8*)owb;
  for (int ks = 0; ks < 16; ++ks){
    const float* src = (ks < 8) ? fcal : cup;
    int ko = (ks & 7)*32 + aquad*8;
    const float4* ap0 = (const float4*)(src + (size_t)(m0 + arow)*256 + ko);
    const float4* ap1 = (const float4*)(src + (size_t)(m0 + 16 + arow)*256 + ko);
    float4 f00 = ap0[0], f01 = ap0[1];
    float4 f10 = ap1[0], f11 = ap1[1];
    bf16x8 a0 = { f2b(f00.x), f2b(f00.y), f2b(f00.z), f2b(f00.w),
                  f2b(f01.x), f2b(f01.y), f2b(f01.z), f2b(f01.w) };
    bf16x8 a1 = { f2b(f10.x), f2b(f10.y), f2b(f10.z), f2b(f10.w),
                  f2b(f11.x), f2b(f11.y), f2b(f11.z), f2b(f11.w) };
    const bf16x8* wp = OW8 + ((size_t)(ks*32 + wave*8))*64 + lane;
#pragma unroll
    for (int t = 0; t < 8; ++t){
      bf16x8 bw = wp[t*64];
      acc[0][t] = MFMA16(a0, bw, acc[0][t]);
      acc[1][t] = MFMA16(a1, bw, acc[1][t]);
    }
  }
#pragma unroll
  for (int t = 0; t < 8; ++t){
    int n = wave*128 + t*16 + (lane & 15);
#pragma unroll
    for (int s = 0; s < 2; ++s)
#pragma unroll
      for (int r = 0; r < 4; ++r){
        int m = m0 + s*16 + aquad*4 + r;
        algb[(size_t)m*512 + n] = f2b(acc[s][t][r]);
      }
  }
}

// om conv3x3 as MFMA implicit GEMM. M-tile 32, N padded 256, phase per ky.
#define XST 520
__global__ __launch_bounds__(256) void k_om(const short* __restrict__ algb,
                                            const short* __restrict__ omwb,
                                            const float* __restrict__ omb,
                                            float* __restrict__ om){
  __shared__ short xbuf[34*XST];
  int m0 = blockIdx.x*32;
  int b = m0 >> 12, y = (m0 & 4095) >> 6, x0 = m0 & 63;
  int tid = threadIdx.x;
  int lane = tid & 63, wave = tid >> 6;
  int arow = lane & 15, aquad = lane >> 4;
  f32x4 acc[2][4];
#pragma unroll
  for (int s = 0; s < 2; ++s)
#pragma unroll
    for (int t = 0; t < 4; ++t) acc[s][t] = (f32x4){0.f,0.f,0.f,0.f};
  const bf16x8* W8 = (const bf16x8*)omwb;
  for (int ky = 0; ky < 3; ++ky){
    int yy = y + ky - 1;
    if ((unsigned)yy >= 64u) continue;           // block-uniform
    __syncthreads();
    const short* srow = algb + (size_t)((b*64 + yy)*64)*512;
    for (int it = 0; it < 9; ++it){
      int idx = it*256 + tid;
      if (idx < 2176){
        int xx = idx >> 6, l8 = idx & 63;
        int gx = x0 - 1 + xx;
        bf16x8 v = (bf16x8){0,0,0,0,0,0,0,0};
        if ((unsigned)gx < 64u) v = *(const bf16x8*)(srow + (size_t)gx*512 + l8*8);
        *(bf16x8*)&xbuf[xx*XST + l8*8] = v;
      }
    }
    __syncthreads();
    for (int ks = 0; ks < 48; ++ks){
      int kl = ks*32 + aquad*8;
      int kx = kl >> 9, cc = kl & 511;
      bf16x8 a0 = *(const bf16x8*)&xbuf[(arow + kx)*XST + cc];
      bf16x8 a1 = *(const bf16x8*)&xbuf[(16 + arow + kx)*XST + cc];
      const bf16x8* wp = W8 + ((size_t)((ky*48 + ks)*16 + wave*4))*64 + lane;
#pragma unroll
      for (int t = 0; t < 4; ++t){
        bf16x8 bw = wp[t*64];
        acc[0][t] = MFMA16(a0, bw, acc[0][t]);
        acc[1][t] = MFMA16(a1, bw, acc[1][t]);
      }
    }
  }
#pragma unroll
  for (int t = 0; t < 4; ++t){
    int f = wave*64 + t*16 + (lane & 15);
    if (f < 216){
      float bias = omb[f];
#pragma unroll
      for (int s = 0; s < 2; ++s)
#pragma unroll
        for (int r = 0; r < 4; ++r){
          int m = m0 + s*16 + (lane >> 4)*4 + r;
          om[(size_t)m*216 + f] = acc[s][t][r] + bias;
        }
    }
  }
}

// DCNv2: params computed once/sample (1 lane each), shuffle-broadcast to 8-lane
// units, r6 coalesced float4 gather, MFMA GEMM. M-tile 16.
#define VST 776
__global__ __launch_bounds__(256) void k_dcn(const float* __restrict__ cup,
                                             const float* __restrict__ om,
                                             const short* __restrict__ dwb,
                                             const float* __restrict__ db,
                                             const float* __restrict__ fcal,
                                             float* __restrict__ out){
  __shared__ short valb[16*VST];   // 24832 B
  int m0 = blockIdx.x*16;
  int b = m0 >> 12, y = (m0 & 4095) >> 6, x0 = m0 & 63;
  int tid = threadIdx.x;
  int lane = tid & 63, wave = tid >> 6;
  int lane8 = tid & 7;
  int ulc = (tid >> 3) & 7;                // consumer unit-local index
  int arow = lane & 15, aquad = lane >> 4;
  f32x4 acc[4];
#pragma unroll
  for (int t = 0; t < 4; ++t) acc[t] = (f32x4){0.f,0.f,0.f,0.f};
  const float4* cb4 = (const float4*)(cup + (size_t)b*4096*256);
  const bf16x8* W8 = (const bf16x8*)dwb;

  for (int ph = 0; ph < 3; ++ph){
    __syncthreads();
    for (int batch = 0; batch < 2; ++batch){
      // producer: this lane owns sample (jglob, unit = wave*8 + (lane&7))
      int jglob = batch*8 + (lane >> 3);
      float wA = 0.f, wB = 0.f, wC = 0.f, wD = 0.f;
      int o00 = 0, o01 = 0, o10 = 0, o11 = 0, colg = 0;
      if (jglob < 12){
        int u = jglob*32 + wave*8 + (lane & 7);
        int i = u / 24; int r = u - i*24; int g = r / 3; int kk = r - g*3;
        const float* omp = om + (size_t)(m0 + i)*216;
        int k = ph*3 + kk;
        float dy = omp[(g*9 + k)*2 + 0];
        float dx = omp[(g*9 + k)*2 + 1];
        float mv = 1.f / (1.f + expf(-omp[144 + g*9 + k]));
        float yp = (float)(y + ph - 1) + dy;
        float xp = (float)(x0 + i + kk - 1) + dx;
        float yf = floorf(yp), xf = floorf(xp);
        float wy = yp - yf, wx = xp - xf;
        int iy = (int)yf, ix = (int)xf;
        wA = (1.f-wy)*(1.f-wx); wB = (1.f-wy)*wx; wC = wy*(1.f-wx); wD = wy*wx;
        bool y0ok = (unsigned)iy < 64u, y1ok = (unsigned)(iy+1) < 64u;
        bool x0ok = (unsigned)ix < 64u, x1ok = (unsigned)(ix+1) < 64u;
        if (!(y0ok && x0ok)) wA = 0.f;
        if (!(y0ok && x1ok)) wB = 0.f;
        if (!(y1ok && x0ok)) wC = 0.f;
        if (!(y1ok && x1ok)) wD = 0.f;
        wA *= mv; wB *= mv; wC *= mv; wD *= mv;
        int y0c = min(max(iy, 0), 63), y1c = min(max(iy + 1, 0), 63);
        int x0c = min(max(ix, 0), 63), x1c = min(max(ix + 1, 0), 63);
        o00 = (y0c*64 + x0c)*64; o01 = (y0c*64 + x1c)*64;
        o10 = (y1c*64 + x0c)*64; o11 = (y1c*64 + x1c)*64;
        colg = (i*VST + kk*256 + g*32) | (g << 16);
      }
      int nj = batch ? 4 : 8;
      for (int jj = 0; jj < nj; ++jj){
        int src = jj*8 + ulc;
        float sA = __shfl(wA, src, 64), sB = __shfl(wB, src, 64);
        float sC = __shfl(wC, src, 64), sD = __shfl(wD, src, 64);
        int s00 = __shfl(o00, src, 64), s01 = __shfl(o01, src, 64);
        int s10 = __shfl(o10, src, 64), s11 = __shfl(o11, src, 64);
        int cg  = __shfl(colg, src, 64);
        int gofs = (cg >> 16)*8 + lane8;
        float4 l00 = cb4[s00 + gofs], l01 = cb4[s01 + gofs];
        float4 l10 = cb4[s10 + gofs], l11 = cb4[s11 + gofs];
        int col = (cg & 0xFFFF) + lane8*4;
        valb[col+0] = f2b(sA*l00.x + sB*l01.x + sC*l10.x + sD*l11.x);
        valb[col+1] = f2b(sA*l00.y + sB*l01.y + sC*l10.y + sD*l11.y);
        valb[col+2] = f2b(sA*l00.z + sB*l01.z + sC*l10.z + sD*l11.z);
        valb[col+3] = f2b(sA*l00.w + sB*l01.w + sC*l10.w + sD*l11.w);
      }
    }
    __syncthreads();
    for (int ks = 0; ks < 24; ++ks){
      bf16x8 a = *(const bf16x8*)&valb[arow*VST + ks*32 + aquad*8];
      const bf16x8* wp = W8 + ((size_t)((ph*24 + ks)*16 + wave*4))*64 + lane;
#pragma unroll
      for (int t = 0; t < 4; ++t)
        acc[t] = MFMA16(a, wp[t*64], acc[t]);
    }
  }
#pragma unroll
  for (int t = 0; t < 4; ++t){
    int f = wave*64 + t*16 + (lane & 15);
    float bias = db[f];
#pragma unroll
    for (int r = 0; r < 4; ++r){
      int m = m0 + aquad*4 + r;
      out[(size_t)m*256 + f] = fmaxf(acc[t][r] + bias, 0.f) + fcal[(size_t)m*256 + f];
    }
  }
}

extern "C" void kernel_launch(void* const* d_in, const int* in_sizes, int n_in,
                              void* d_out, int out_size, void* d_ws, size_t ws_size,
                              hipStream_t stream){
  const float* fine     = (const float*)d_in[0];
  const float* coarse   = (const float*)d_in[1];
  const float* attend_w = (const float*)d_in[2];
  const float* select_w = (const float*)d_in[3];
  const float* offset_w = (const float*)d_in[4];
  const float* om_w     = (const float*)d_in[5];
  const float* om_b     = (const float*)d_in[6];
  const float* dcn_w    = (const float*)d_in[7];
  const float* dcn_b    = (const float*)d_in[8];
  float* out = (float*)d_out;
  float* ws  = (float*)d_ws;

  float* gate = ws + OFS_GATE;
  float* part = ws + OFS_PART;
  float* cup  = ws + OFS_CUP;
  float* fcal = ws + OFS_FCAL;
  short* algb = (short*)(ws + OFS_ALGB);
  float* om   = ws + OFS_OM;
  short* dwb  = (short*)(ws + OFS_DWB);
  short* omwb = (short*)(ws + OFS_OMWB);
  short* wbb  = (short*)(ws + OFS_WBB);
  short* owb  = (short*)(ws + OFS_OWB);

  hipLaunchKernelGGL(k_gap,        dim3(256),  dim3(256), 0, stream, fine, part);
  hipLaunchKernelGGL(k_attn,       dim3(4),    dim3(256), 0, stream, part, attend_w, gate);
  hipLaunchKernelGGL(k_foldw_frag, dim3(128),  dim3(256), 0, stream, gate, select_w, wbb);
  hipLaunchKernelGGL(k_cvtw,       dim3(992),  dim3(256), 0, stream, dcn_w, om_w, offset_w, dwb, omwb, owb);
  hipLaunchKernelGGL(k_up,         dim3(4096), dim3(256), 0, stream, coarse, cup);
  hipLaunchKernelGGL(k_fcal,       dim3(512),  dim3(256), 0, stream, fine, wbb, fcal);
  hipLaunchKernelGGL(k_align,      dim3(512),  dim3(256), 0, stream, fcal, cup, owb, algb);
  hipLaunchKernelGGL(k_om,         dim3(512),  dim3(256), 0, stream, algb, omwb, om_b, om);
  hipLaunchKernelGGL(k_dcn,        dim3(1024), dim3(256), 0, stream, cup, om, dwb, dcn_b, fcal, out);
  (void)in_sizes; (void)n_in; (void)out_size; (void)ws_size;
}

// Round 9
// 284.314 us; speedup vs baseline: 1.2587x; 1.2385x over previous
//
#include <hip/hip_runtime.h>
#include <math.h>

// B=4, H=W=64, C=256, DG=8, K=3, cpg=32; coarse: [4,32,32,256]

typedef __attribute__((ext_vector_type(8))) short bf16x8;
typedef __attribute__((ext_vector_type(4))) short bf16x4;
typedef __attribute__((ext_vector_type(4))) float f32x4;
#define MFMA16(a,b,c) __builtin_amdgcn_mfma_f32_16x16x32_bf16(a,b,c,0,0,0)

__device__ inline short f2b(float x){
  union { float f; unsigned u; } v; v.f = x;
  unsigned r = v.u + 0x7FFFu + ((v.u >> 16) & 1u);
  return (short)(r >> 16);
}
__device__ inline float b2f(short s){
  union { unsigned u; float f; } v;
  v.u = ((unsigned)(unsigned short)s) << 16;
  return v.f;
}

// workspace layout (float offsets)
#define OFS_GATE  1024u
#define OFS_PART  2048u        // f32 [256][256] gap partials
#define OFS_CUPB  264192u      // bf16 [4][64][64][256] (2097152 slots)
#define OFS_FCAL  4458496u     // f32  [16384][256]
#define OFS_ALGB  8652800u     // bf16 [16384][512]
#define OFS_OM    12847104u    // f32  [16384][216]
#define OFS_DWB   16386048u    // bf16 frag [72][16][64][8]
#define OFS_OMWB  16680960u    // bf16 frag [144][16][64][8]
#define OFS_SWB   17270784u    // bf16 frag [8][16][64][8]
#define OFS_OWB   17401856u    // bf16 frag [16][32][64][8]

// GAP partials: 256 blocks (b*64+chunk), float4 loads, LDS reduce, no atomics
__global__ __launch_bounds__(256) void k_gap(const float* __restrict__ fine,
                                             float* __restrict__ part){
  __shared__ float red[4*256];
  int b = blockIdx.x >> 6, chunk = blockIdx.x & 63;
  int c4 = threadIdx.x & 63, rl = threadIdx.x >> 6;
  const float4* F4 = (const float4*)fine;
  float4 s = {0.f,0.f,0.f,0.f};
  for (int it = 0; it < 16; ++it){
    int row = chunk*64 + it*4 + rl;
    float4 v = F4[((size_t)(b*4096 + row))*64 + c4];
    s.x += v.x; s.y += v.y; s.z += v.z; s.w += v.w;
  }
  *(float4*)&red[rl*256 + c4*4] = s;
  __syncthreads();
  int c = threadIdx.x;
  part[(size_t)blockIdx.x*256 + c] = red[c] + red[256+c] + red[512+c] + red[768+c];
}

// fused: attn (blocks 0-3) + weight frag cvt (dwb/omwb/owb/swb) + upsample->bf16
__global__ __launch_bounds__(256) void k_misc(const float* __restrict__ part,
                                              const float* __restrict__ aw,
                                              float* __restrict__ gate,
                                              const float* __restrict__ dw,
                                              const float* __restrict__ omw,
                                              const float* __restrict__ ow,
                                              const float* __restrict__ sw,
                                              short* __restrict__ dwb,
                                              short* __restrict__ omwb,
                                              short* __restrict__ owb,
                                              short* __restrict__ swb,
                                              const float* __restrict__ coarse,
                                              short* __restrict__ cupb){
  int blk = blockIdx.x;
  if (blk < 4){
    __shared__ float m[256];
    int b = blk, f = threadIdx.x;
    float sm = 0.f;
    for (int ch = 0; ch < 64; ++ch) sm += part[(size_t)(b*64 + ch)*256 + f];
    m[f] = sm * (1.f/4096.f);
    __syncthreads();
    float s = 0.f;
    for (int c = 0; c < 256; ++c) s += m[c] * aw[c*256 + f];
    gate[b*256 + f] = 1.f + 1.f/(1.f + expf(-s));
  } else if (blk < 292){
    int t = (blk - 4)*256 + threadIdx.x;         // 73728
    int l = t & 63, nt = (t >> 6) & 15, ksg = t >> 10;
    int n = nt*16 + (l & 15);
    int kb = ksg*32 + (l >> 4)*8;
    bf16x8 o;
#pragma unroll
    for (int j = 0; j < 8; ++j) o[j] = f2b(dw[(size_t)(kb + j)*256 + n]);
    ((bf16x8*)dwb)[t] = o;
  } else if (blk < 868){
    int t = (blk - 292)*256 + threadIdx.x;       // 147456
    int l = t & 63, nt = (t >> 6) & 15, ksg = t >> 10;
    int n = nt*16 + (l & 15);
    int kb = ksg*32 + (l >> 4)*8;
    bf16x8 o;
#pragma unroll
    for (int j = 0; j < 8; ++j)
      o[j] = (n < 216) ? f2b(omw[(size_t)(kb + j)*216 + n]) : (short)0;
    ((bf16x8*)omwb)[t] = o;
  } else if (blk < 996){
    int t = (blk - 868)*256 + threadIdx.x;       // 32768
    int l = t & 63, nt = (t >> 6) & 31, ksg = t >> 11;
    int n = nt*16 + (l & 15);
    int kb = ksg*32 + (l >> 4)*8;
    float sc = (kb >= 256) ? 2.f : 1.f;
    bf16x8 o;
#pragma unroll
    for (int j = 0; j < 8; ++j) o[j] = f2b(sc * ow[(size_t)(kb + j)*512 + n]);
    ((bf16x8*)owb)[t] = o;
  } else if (blk < 1124){
    int t = (blk - 996)*256 + threadIdx.x;       // 32768
    int l = t & 63, nt = (t >> 6) & 15, ksg = t >> 10;
    int n = nt*16 + (l & 15);
    int kb = ksg*32 + (l >> 4)*8;
    bf16x8 o;
#pragma unroll
    for (int j = 0; j < 8; ++j) o[j] = f2b(sw[(size_t)(kb + j)*256 + n]);
    ((bf16x8*)swb)[t] = o;
  } else {
    int idx = (blk - 1124)*256 + threadIdx.x;    // B*64*64*64 4-ch units
    int c4 = idx & 63, x = (idx >> 6) & 63, y = (idx >> 12) & 63, b = idx >> 18;
    float fy = 0.5f*y - 0.25f, fx = 0.5f*x - 0.25f;
    float yf = floorf(fy), xf = floorf(fx);
    float wy = fy - yf, wx = fx - xf;
    int r0 = max(0, min(31, (int)yf)), r1 = max(0, min(31, (int)yf + 1));
    int c0 = max(0, min(31, (int)xf)), c1 = max(0, min(31, (int)xf + 1));
    const float4* src = (const float4*)coarse;
    float4 v00 = src[((b*32 + r0)*32 + c0)*64 + c4];
    float4 v01 = src[((b*32 + r0)*32 + c1)*64 + c4];
    float4 v10 = src[((b*32 + r1)*32 + c0)*64 + c4];
    float4 v11 = src[((b*32 + r1)*32 + c1)*64 + c4];
    float w00 = (1.f-wy)*(1.f-wx), w01 = (1.f-wy)*wx, w10 = wy*(1.f-wx), w11 = wy*wx;
    bf16x4 o = { f2b(v00.x*w00 + v01.x*w01 + v10.x*w10 + v11.x*w11),
                 f2b(v00.y*w00 + v01.y*w01 + v10.y*w10 + v11.y*w11),
                 f2b(v00.z*w00 + v01.z*w01 + v10.z*w10 + v11.z*w11),
                 f2b(v00.w*w00 + v01.w*w01 + v10.w*w10 + v11.w*w11) };
    ((bf16x4*)cupb)[idx] = o;
  }
}

// fused fcal+align: stage (fine*gate)->bf16 LDS, GEMM1->fcal, C->A via LDS,
// GEMM2 (concat with cupb rows) -> algb. M-tile 32.
#define FST 264
__global__ __launch_bounds__(256) void k_fa(const float* __restrict__ fine,
                                            const float* __restrict__ gate,
                                            const short* __restrict__ swb,
                                            const short* __restrict__ owb,
                                            const short* __restrict__ cupb,
                                            float* __restrict__ fcal,
                                            short* __restrict__ algb){
  __shared__ float g4[256];
  __shared__ short ab[32*FST];
  int m0 = blockIdx.x*32, b = m0 >> 12;
  int tid = threadIdx.x, lane = tid & 63, wave = tid >> 6;
  int arow = lane & 15, aquad = lane >> 4;
  g4[tid] = gate[b*256 + tid];
  __syncthreads();
  const float4* F4 = (const float4*)(fine + (size_t)m0*256);
  const float4* G4 = (const float4*)g4;
  for (int it = 0; it < 8; ++it){
    int idx = it*256 + tid;
    int row = idx >> 6, c4 = idx & 63;
    float4 v = F4[row*64 + c4];
    float4 gg = G4[c4];
    bf16x4 s4 = { f2b(v.x*gg.x), f2b(v.y*gg.y), f2b(v.z*gg.z), f2b(v.w*gg.w) };
    *(bf16x4*)&ab[row*FST + c4*4] = s4;
  }
  __syncthreads();
  // GEMM1: fcal tile
  f32x4 acc[2][4];
#pragma unroll
  for (int s = 0; s < 2; ++s)
#pragma unroll
    for (int t = 0; t < 4; ++t) acc[s][t] = (f32x4){0.f,0.f,0.f,0.f};
  const bf16x8* W8 = (const bf16x8*)swb;
  for (int ks = 0; ks < 8; ++ks){
    bf16x8 a0 = *(const bf16x8*)&ab[arow*FST + ks*32 + aquad*8];
    bf16x8 a1 = *(const bf16x8*)&ab[(16 + arow)*FST + ks*32 + aquad*8];
    const bf16x8* wp = W8 + ((size_t)(ks*16 + wave*4))*64 + lane;
#pragma unroll
    for (int t = 0; t < 4; ++t){
      bf16x8 bw = wp[t*64];
      acc[0][t] = MFMA16(a0, bw, acc[0][t]);
      acc[1][t] = MFMA16(a1, bw, acc[1][t]);
    }
  }
  __syncthreads();   // all GEMM1 LDS reads done before overwrite
  // epilogue1: fcal fp32 global + bf16 back to LDS (C->A transform)
#pragma unroll
  for (int t = 0; t < 4; ++t){
    int f = wave*64 + t*16 + arow;
#pragma unroll
    for (int s = 0; s < 2; ++s)
#pragma unroll
      for (int r = 0; r < 4; ++r){
        int mloc = s*16 + aquad*4 + r;
        float v = acc[s][t][r];
        fcal[(size_t)(m0 + mloc)*256 + f] = v;
        ab[mloc*FST + f] = f2b(v);
      }
  }
  __syncthreads();
  // GEMM2: concat(fcal_b, cupb) @ owb
  f32x4 acc2[2][8];
#pragma unroll
  for (int s = 0; s < 2; ++s)
#pragma unroll
    for (int t = 0; t < 8; ++t) acc2[s][t] = (f32x4){0.f,0.f,0.f,0.f};
  const bf16x8* OW8 = (const bf16x8*)owb;
  for (int ks = 0; ks < 16; ++ks){
    bf16x8 a0, a1;
    if (ks < 8){
      a0 = *(const bf16x8*)&ab[arow*FST + ks*32 + aquad*8];
      a1 = *(const bf16x8*)&ab[(16 + arow)*FST + ks*32 + aquad*8];
    } else {
      int ko = (ks - 8)*32 + aquad*8;
      a0 = *(const bf16x8*)(cupb + (size_t)(m0 + arow)*256 + ko);
      a1 = *(const bf16x8*)(cupb + (size_t)(m0 + 16 + arow)*256 + ko);
    }
    const bf16x8* wp = OW8 + ((size_t)(ks*32 + wave*8))*64 + lane;
#pragma unroll
    for (int t = 0; t < 8; ++t){
      bf16x8 bw = wp[t*64];
      acc2[0][t] = MFMA16(a0, bw, acc2[0][t]);
      acc2[1][t] = MFMA16(a1, bw, acc2[1][t]);
    }
  }
#pragma unroll
  for (int t = 0; t < 8; ++t){
    int n = wave*128 + t*16 + arow;
#pragma unroll
    for (int s = 0; s < 2; ++s)
#pragma unroll
      for (int r = 0; r < 4; ++r){
        int m = m0 + s*16 + aquad*4 + r;
        algb[(size_t)m*512 + n] = f2b(acc2[s][t][r]);
      }
  }
}

// om conv3x3 as MFMA implicit GEMM. M-tile 32, N padded 256, phase per ky.
#define XST 520
__global__ __launch_bounds__(256) void k_om(const short* __restrict__ algb,
                                            const short* __restrict__ omwb,
                                            const float* __restrict__ omb,
                                            float* __restrict__ om){
  __shared__ short xbuf[34*XST];
  int m0 = blockIdx.x*32;
  int b = m0 >> 12, y = (m0 & 4095) >> 6, x0 = m0 & 63;
  int tid = threadIdx.x;
  int lane = tid & 63, wave = tid >> 6;
  int arow = lane & 15, aquad = lane >> 4;
  f32x4 acc[2][4];
#pragma unroll
  for (int s = 0; s < 2; ++s)
#pragma unroll
    for (int t = 0; t < 4; ++t) acc[s][t] = (f32x4){0.f,0.f,0.f,0.f};
  const bf16x8* W8 = (const bf16x8*)omwb;
  for (int ky = 0; ky < 3; ++ky){
    int yy = y + ky - 1;
    if ((unsigned)yy >= 64u) continue;           // block-uniform
    __syncthreads();
    const short* srow = algb + (size_t)((b*64 + yy)*64)*512;
    for (int it = 0; it < 9; ++it){
      int idx = it*256 + tid;
      if (idx < 2176){
        int xx = idx >> 6, l8 = idx & 63;
        int gx = x0 - 1 + xx;
        bf16x8 v = (bf16x8){0,0,0,0,0,0,0,0};
        if ((unsigned)gx < 64u) v = *(const bf16x8*)(srow + (size_t)gx*512 + l8*8);
        *(bf16x8*)&xbuf[xx*XST + l8*8] = v;
      }
    }
    __syncthreads();
    for (int ks = 0; ks < 48; ++ks){
      int kl = ks*32 + aquad*8;
      int kx = kl >> 9, cc = kl & 511;
      bf16x8 a0 = *(const bf16x8*)&xbuf[(arow + kx)*XST + cc];
      bf16x8 a1 = *(const bf16x8*)&xbuf[(16 + arow + kx)*XST + cc];
      const bf16x8* wp = W8 + ((size_t)((ky*48 + ks)*16 + wave*4))*64 + lane;
#pragma unroll
      for (int t = 0; t < 4; ++t){
        bf16x8 bw = wp[t*64];
        acc[0][t] = MFMA16(a0, bw, acc[0][t]);
        acc[1][t] = MFMA16(a1, bw, acc[1][t]);
      }
    }
  }
#pragma unroll
  for (int t = 0; t < 4; ++t){
    int f = wave*64 + t*16 + (lane & 15);
    if (f < 216){
      float bias = omb[f];
#pragma unroll
      for (int s = 0; s < 2; ++s)
#pragma unroll
        for (int r = 0; r < 4; ++r){
          int m = m0 + s*16 + (lane >> 4)*4 + r;
          om[(size_t)m*216 + f] = acc[s][t][r] + bias;
        }
    }
  }
}

// DCNv2: r6-style staging (params in-register per 4-lane unit), bf16 gather
// from cupb (bf16x8/lane, 64B/corner per unit), MFMA GEMM. M-tile 16.
#define VST 776
__global__ __launch_bounds__(256) void k_dcn(const short* __restrict__ cupb,
                                             const float* __restrict__ om,
                                             const short* __restrict__ dwb,
                                             const float* __restrict__ db,
                                             const float* __restrict__ fcal,
                                             float* __restrict__ out){
  __shared__ short valb[16*VST];   // 24832 B
  int m0 = blockIdx.x*16;
  int b = m0 >> 12, y = (m0 & 4095) >> 6, x0 = m0 & 63;
  int tid = threadIdx.x;
  int lane = tid & 63, wave = tid >> 6;
  int unit = tid >> 2, lane4 = tid & 3;    // 64 units x 4 lanes
  int arow = lane & 15, aquad = lane >> 4;
  f32x4 acc[4];
#pragma unroll
  for (int t = 0; t < 4; ++t) acc[t] = (f32x4){0.f,0.f,0.f,0.f};
  const short* cpb = cupb + (size_t)b*4096*256;
  const bf16x8* W8 = (const bf16x8*)dwb;

  for (int ph = 0; ph < 3; ++ph){
    __syncthreads();
    // 384 samples (16 rows x 8 g x 3 taps); 64 units, 6 iters, 8 ch/lane
    for (int it = 0; it < 6; ++it){
      int u = it*64 + unit;
      int i = u / 24; int r = u - i*24; int g = r / 3; int kk = r - g*3;
      const float* omp = om + (size_t)(m0 + i)*216;
      int k = ph*3 + kk;
      float dy = omp[(g*9 + k)*2 + 0];
      float dx = omp[(g*9 + k)*2 + 1];
      float mv = 1.f / (1.f + expf(-omp[144 + g*9 + k]));
      float yp = (float)(y + ph - 1) + dy;
      float xp = (float)(x0 + i + kk - 1) + dx;
      float yf = floorf(yp), xf = floorf(xp);
      float wy = yp - yf, wx = xp - xf;
      int iy = (int)yf, ix = (int)xf;
      float wA = (1.f-wy)*(1.f-wx), wB = (1.f-wy)*wx, wC = wy*(1.f-wx), wD = wy*wx;
      bool y0ok = (unsigned)iy < 64u, y1ok = (unsigned)(iy+1) < 64u;
      bool x0ok = (unsigned)ix < 64u, x1ok = (unsigned)(ix+1) < 64u;
      if (!(y0ok && x0ok)) wA = 0.f;
      if (!(y0ok && x1ok)) wB = 0.f;
      if (!(y1ok && x0ok)) wC = 0.f;
      if (!(y1ok && x1ok)) wD = 0.f;
      int y0c = min(max(iy, 0), 63), y1c = min(max(iy + 1, 0), 63);
      int x0c = min(max(ix, 0), 63), x1c = min(max(ix + 1, 0), 63);
      int cofs = g*32 + lane4*8;
      bf16x8 l00 = *(const bf16x8*)(cpb + (size_t)(y0c*64 + x0c)*256 + cofs);
      bf16x8 l01 = *(const bf16x8*)(cpb + (size_t)(y0c*64 + x1c)*256 + cofs);
      bf16x8 l10 = *(const bf16x8*)(cpb + (size_t)(y1c*64 + x0c)*256 + cofs);
      bf16x8 l11 = *(const bf16x8*)(cpb + (size_t)(y1c*64 + x1c)*256 + cofs);
      bf16x8 o;
#pragma unroll
      for (int j = 0; j < 8; ++j){
        float v = wA*b2f(l00[j]) + wB*b2f(l01[j]) + wC*b2f(l10[j]) + wD*b2f(l11[j]);
        o[j] = f2b(v * mv);
      }
      *(bf16x8*)&valb[i*VST + kk*256 + g*32 + lane4*8] = o;
    }
    __syncthreads();
    for (int ks = 0; ks < 24; ++ks){
      bf16x8 a = *(const bf16x8*)&valb[arow*VST + ks*32 + aquad*8];
      const bf16x8* wp = W8 + ((size_t)((ph*24 + ks)*16 + wave*4))*64 + lane;
#pragma unroll
      for (int t = 0; t < 4; ++t)
        acc[t] = MFMA16(a, wp[t*64], acc[t]);
    }
  }
#pragma unroll
  for (int t = 0; t < 4; ++t){
    int f = wave*64 + t*16 + (lane & 15);
    float bias = db[f];
#pragma unroll
    for (int r = 0; r < 4; ++r){
      int m = m0 + aquad*4 + r;
      out[(size_t)m*256 + f] = fmaxf(acc[t][r] + bias, 0.f) + fcal[(size_t)m*256 + f];
    }
  }
}

extern "C" void kernel_launch(void* const* d_in, const int* in_sizes, int n_in,
                              void* d_out, int out_size, void* d_ws, size_t ws_size,
                              hipStream_t stream){
  const float* fine     = (const float*)d_in[0];
  const float* coarse   = (const float*)d_in[1];
  const float* attend_w = (const float*)d_in[2];
  const float* select_w = (const float*)d_in[3];
  const float* offset_w = (const float*)d_in[4];
  const float* om_w     = (const float*)d_in[5];
  const float* om_b     = (const float*)d_in[6];
  const float* dcn_w    = (const float*)d_in[7];
  const float* dcn_b    = (const float*)d_in[8];
  float* out = (float*)d_out;
  float* ws  = (float*)d_ws;

  float* gate = ws + OFS_GATE;
  float* part = ws + OFS_PART;
  short* cupb = (short*)(ws + OFS_CUPB);
  float* fcal = ws + OFS_FCAL;
  short* algb = (short*)(ws + OFS_ALGB);
  float* om   = ws + OFS_OM;
  short* dwb  = (short*)(ws + OFS_DWB);
  short* omwb = (short*)(ws + OFS_OMWB);
  short* swb  = (short*)(ws + OFS_SWB);
  short* owb  = (short*)(ws + OFS_OWB);

  hipLaunchKernelGGL(k_gap,  dim3(256),  dim3(256), 0, stream, fine, part);
  hipLaunchKernelGGL(k_misc, dim3(5220), dim3(256), 0, stream, part, attend_w, gate,
                     dcn_w, om_w, offset_w, select_w, dwb, omwb, owb, swb, coarse, cupb);
  hipLaunchKernelGGL(k_fa,   dim3(512),  dim3(256), 0, stream, fine, gate, swb, owb,
                     cupb, fcal, algb);
  hipLaunchKernelGGL(k_om,   dim3(512),  dim3(256), 0, stream, algb, omwb, om_b, om);
  hipLaunchKernelGGL(k_dcn,  dim3(1024), dim3(256), 0, stream, cupb, om, dwb, dcn_b, fcal, out);
  (void)in_sizes; (void)n_in; (void)out_size; (void)ws_size;
}

// Round 10
// 282.376 us; speedup vs baseline: 1.2673x; 1.0069x over previous
//
#include <hip/hip_runtime.h>
#include <math.h>

// B=4, H=W=64, C=256, DG=8, K=3, cpg=32; coarse: [4,32,32,256]

typedef __attribute__((ext_vector_type(8))) short bf16x8;
typedef __attribute__((ext_vector_type(4))) short bf16x4;
typedef __attribute__((ext_vector_type(4))) float f32x4;
#define MFMA16(a,b,c) __builtin_amdgcn_mfma_f32_16x16x32_bf16(a,b,c,0,0,0)

__device__ inline short f2b(float x){
  union { float f; unsigned u; } v; v.f = x;
  unsigned r = v.u + 0x7FFFu + ((v.u >> 16) & 1u);
  return (short)(r >> 16);
}
__device__ inline float b2f(short s){
  union { unsigned u; float f; } v;
  v.u = ((unsigned)(unsigned short)s) << 16;
  return v.f;
}

// workspace layout (float offsets)
#define OFS_GATE  1024u
#define OFS_PART  2048u        // f32 [256][256] gap partials
#define OFS_CUPB  264192u      // bf16 [4][64][64][256]
#define OFS_FCAL  4458496u     // f32  [16384][256]
#define OFS_ALGB  8652800u     // bf16 [16384][512]
#define OFS_OM    12847104u    // f32  [16384][216]
#define OFS_DWB   16386048u    // bf16 frag [72][16][64][8]
#define OFS_OMWB  16680960u    // bf16 frag [144][16][64][8]
#define OFS_SWB   17270784u    // bf16 frag [8][16][64][8]
#define OFS_OWB   17401856u    // bf16 frag [16][32][64][8]

// GAP partials: 256 blocks (b*64+chunk), float4 loads, LDS reduce, no atomics
__global__ __launch_bounds__(256) void k_gap(const float* __restrict__ fine,
                                             float* __restrict__ part){
  __shared__ float red[4*256];
  int b = blockIdx.x >> 6, chunk = blockIdx.x & 63;
  int c4 = threadIdx.x & 63, rl = threadIdx.x >> 6;
  const float4* F4 = (const float4*)fine;
  float4 s = {0.f,0.f,0.f,0.f};
  for (int it = 0; it < 16; ++it){
    int row = chunk*64 + it*4 + rl;
    float4 v = F4[((size_t)(b*4096 + row))*64 + c4];
    s.x += v.x; s.y += v.y; s.z += v.z; s.w += v.w;
  }
  *(float4*)&red[rl*256 + c4*4] = s;
  __syncthreads();
  int c = threadIdx.x;
  part[(size_t)blockIdx.x*256 + c] = red[c] + red[256+c] + red[512+c] + red[768+c];
}

// fused: attn (blocks 0-3) + weight frag cvt (dwb/omwb/owb/swb) + upsample->bf16
__global__ __launch_bounds__(256) void k_misc(const float* __restrict__ part,
                                              const float* __restrict__ aw,
                                              float* __restrict__ gate,
                                              const float* __restrict__ dw,
                                              const float* __restrict__ omw,
                                              const float* __restrict__ ow,
                                              const float* __restrict__ sw,
                                              short* __restrict__ dwb,
                                              short* __restrict__ omwb,
                                              short* __restrict__ owb,
                                              short* __restrict__ swb,
                                              const float* __restrict__ coarse,
                                              short* __restrict__ cupb){
  int blk = blockIdx.x;
  if (blk < 4){
    __shared__ float m[256];
    int b = blk, f = threadIdx.x;
    float sm = 0.f;
    for (int ch = 0; ch < 64; ++ch) sm += part[(size_t)(b*64 + ch)*256 + f];
    m[f] = sm * (1.f/4096.f);
    __syncthreads();
    float s = 0.f;
    for (int c = 0; c < 256; ++c) s += m[c] * aw[c*256 + f];
    gate[b*256 + f] = 1.f + 1.f/(1.f + expf(-s));
  } else if (blk < 292){
    int t = (blk - 4)*256 + threadIdx.x;         // 73728
    int l = t & 63, nt = (t >> 6) & 15, ksg = t >> 10;
    int n = nt*16 + (l & 15);
    int kb = ksg*32 + (l >> 4)*8;
    bf16x8 o;
#pragma unroll
    for (int j = 0; j < 8; ++j) o[j] = f2b(dw[(size_t)(kb + j)*256 + n]);
    ((bf16x8*)dwb)[t] = o;
  } else if (blk < 868){
    int t = (blk - 292)*256 + threadIdx.x;       // 147456
    int l = t & 63, nt = (t >> 6) & 15, ksg = t >> 10;
    int n = nt*16 + (l & 15);
    int kb = ksg*32 + (l >> 4)*8;
    bf16x8 o;
#pragma unroll
    for (int j = 0; j < 8; ++j)
      o[j] = (n < 216) ? f2b(omw[(size_t)(kb + j)*216 + n]) : (short)0;
    ((bf16x8*)omwb)[t] = o;
  } else if (blk < 996){
    int t = (blk - 868)*256 + threadIdx.x;       // 32768
    int l = t & 63, nt = (t >> 6) & 31, ksg = t >> 11;
    int n = nt*16 + (l & 15);
    int kb = ksg*32 + (l >> 4)*8;
    float sc = (kb >= 256) ? 2.f : 1.f;
    bf16x8 o;
#pragma unroll
    for (int j = 0; j < 8; ++j) o[j] = f2b(sc * ow[(size_t)(kb + j)*512 + n]);
    ((bf16x8*)owb)[t] = o;
  } else if (blk < 1124){
    int t = (blk - 996)*256 + threadIdx.x;       // 32768
    int l = t & 63, nt = (t >> 6) & 15, ksg = t >> 10;
    int n = nt*16 + (l & 15);
    int kb = ksg*32 + (l >> 4)*8;
    bf16x8 o;
#pragma unroll
    for (int j = 0; j < 8; ++j) o[j] = f2b(sw[(size_t)(kb + j)*256 + n]);
    ((bf16x8*)swb)[t] = o;
  } else {
    int idx = (blk - 1124)*256 + threadIdx.x;    // B*64*64*64 4-ch units
    int c4 = idx & 63, x = (idx >> 6) & 63, y = (idx >> 12) & 63, b = idx >> 18;
    float fy = 0.5f*y - 0.25f, fx = 0.5f*x - 0.25f;
    float yf = floorf(fy), xf = floorf(fx);
    float wy = fy - yf, wx = fx - xf;
    int r0 = max(0, min(31, (int)yf)), r1 = max(0, min(31, (int)yf + 1));
    int c0 = max(0, min(31, (int)xf)), c1 = max(0, min(31, (int)xf + 1));
    const float4* src = (const float4*)coarse;
    float4 v00 = src[((b*32 + r0)*32 + c0)*64 + c4];
    float4 v01 = src[((b*32 + r0)*32 + c1)*64 + c4];
    float4 v10 = src[((b*32 + r1)*32 + c0)*64 + c4];
    float4 v11 = src[((b*32 + r1)*32 + c1)*64 + c4];
    float w00 = (1.f-wy)*(1.f-wx), w01 = (1.f-wy)*wx, w10 = wy*(1.f-wx), w11 = wy*wx;
    bf16x4 o = { f2b(v00.x*w00 + v01.x*w01 + v10.x*w10 + v11.x*w11),
                 f2b(v00.y*w00 + v01.y*w01 + v10.y*w10 + v11.y*w11),
                 f2b(v00.z*w00 + v01.z*w01 + v10.z*w10 + v11.z*w11),
                 f2b(v00.w*w00 + v01.w*w01 + v10.w*w10 + v11.w*w11) };
    ((bf16x4*)cupb)[idx] = o;
  }
}

// fused fcal+align: stage (fine*gate)->bf16 LDS, GEMM1->fcal, C->A via LDS,
// GEMM2 (concat with cupb rows) -> algb. M-tile 32.
#define FST 264
__global__ __launch_bounds__(256) void k_fa(const float* __restrict__ fine,
                                            const float* __restrict__ gate,
                                            const short* __restrict__ swb,
                                            const short* __restrict__ owb,
                                            const short* __restrict__ cupb,
                                            float* __restrict__ fcal,
                                            short* __restrict__ algb){
  __shared__ float g4[256];
  __shared__ short ab[32*FST];
  int m0 = blockIdx.x*32, b = m0 >> 12;
  int tid = threadIdx.x, lane = tid & 63, wave = tid >> 6;
  int arow = lane & 15, aquad = lane >> 4;
  g4[tid] = gate[b*256 + tid];
  __syncthreads();
  const float4* F4 = (const float4*)(fine + (size_t)m0*256);
  const float4* G4 = (const float4*)g4;
  for (int it = 0; it < 8; ++it){
    int idx = it*256 + tid;
    int row = idx >> 6, c4 = idx & 63;
    float4 v = F4[row*64 + c4];
    float4 gg = G4[c4];
    bf16x4 s4 = { f2b(v.x*gg.x), f2b(v.y*gg.y), f2b(v.z*gg.z), f2b(v.w*gg.w) };
    *(bf16x4*)&ab[row*FST + c4*4] = s4;
  }
  __syncthreads();
  f32x4 acc[2][4];
#pragma unroll
  for (int s = 0; s < 2; ++s)
#pragma unroll
    for (int t = 0; t < 4; ++t) acc[s][t] = (f32x4){0.f,0.f,0.f,0.f};
  const bf16x8* W8 = (const bf16x8*)swb;
  for (int ks = 0; ks < 8; ++ks){
    bf16x8 a0 = *(const bf16x8*)&ab[arow*FST + ks*32 + aquad*8];
    bf16x8 a1 = *(const bf16x8*)&ab[(16 + arow)*FST + ks*32 + aquad*8];
    const bf16x8* wp = W8 + ((size_t)(ks*16 + wave*4))*64 + lane;
#pragma unroll
    for (int t = 0; t < 4; ++t){
      bf16x8 bw = wp[t*64];
      acc[0][t] = MFMA16(a0, bw, acc[0][t]);
      acc[1][t] = MFMA16(a1, bw, acc[1][t]);
    }
  }
  __syncthreads();
#pragma unroll
  for (int t = 0; t < 4; ++t){
    int f = wave*64 + t*16 + arow;
#pragma unroll
    for (int s = 0; s < 2; ++s)
#pragma unroll
      for (int r = 0; r < 4; ++r){
        int mloc = s*16 + aquad*4 + r;
        float v = acc[s][t][r];
        fcal[(size_t)(m0 + mloc)*256 + f] = v;
        ab[mloc*FST + f] = f2b(v);
      }
  }
  __syncthreads();
  f32x4 acc2[2][8];
#pragma unroll
  for (int s = 0; s < 2; ++s)
#pragma unroll
    for (int t = 0; t < 8; ++t) acc2[s][t] = (f32x4){0.f,0.f,0.f,0.f};
  const bf16x8* OW8 = (const bf16x8*)owb;
  for (int ks = 0; ks < 16; ++ks){
    bf16x8 a0, a1;
    if (ks < 8){
      a0 = *(const bf16x8*)&ab[arow*FST + ks*32 + aquad*8];
      a1 = *(const bf16x8*)&ab[(16 + arow)*FST + ks*32 + aquad*8];
    } else {
      int ko = (ks - 8)*32 + aquad*8;
      a0 = *(const bf16x8*)(cupb + (size_t)(m0 + arow)*256 + ko);
      a1 = *(const bf16x8*)(cupb + (size_t)(m0 + 16 + arow)*256 + ko);
    }
    const bf16x8* wp = OW8 + ((size_t)(ks*32 + wave*8))*64 + lane;
#pragma unroll
    for (int t = 0; t < 8; ++t){
      bf16x8 bw = wp[t*64];
      acc2[0][t] = MFMA16(a0, bw, acc2[0][t]);
      acc2[1][t] = MFMA16(a1, bw, acc2[1][t]);
    }
  }
#pragma unroll
  for (int t = 0; t < 8; ++t){
    int n = wave*128 + t*16 + arow;
#pragma unroll
    for (int s = 0; s < 2; ++s)
#pragma unroll
      for (int r = 0; r < 4; ++r){
        int m = m0 + s*16 + aquad*4 + r;
        algb[(size_t)m*512 + n] = f2b(acc2[s][t][r]);
      }
  }
}

// om conv3x3 as MFMA implicit GEMM. M-tile 32, N-split (half of 256 per block),
// grid 1024 for occupancy; phase per ky.
#define XST 520
__global__ __launch_bounds__(256) void k_om(const short* __restrict__ algb,
                                            const short* __restrict__ omwb,
                                            const float* __restrict__ omb,
                                            float* __restrict__ om){
  __shared__ short xbuf[34*XST];
  int blk = blockIdx.x;
  int m0 = (blk >> 1)*32, nh = blk & 1;
  int b = m0 >> 12, y = (m0 & 4095) >> 6, x0 = m0 & 63;
  int tid = threadIdx.x;
  int lane = tid & 63, wave = tid >> 6;
  int arow = lane & 15, aquad = lane >> 4;
  f32x4 acc[2][2];
#pragma unroll
  for (int s = 0; s < 2; ++s)
#pragma unroll
    for (int t = 0; t < 2; ++t) acc[s][t] = (f32x4){0.f,0.f,0.f,0.f};
  const bf16x8* W8 = (const bf16x8*)omwb;
  for (int ky = 0; ky < 3; ++ky){
    int yy = y + ky - 1;
    if ((unsigned)yy >= 64u) continue;           // block-uniform
    __syncthreads();
    const short* srow = algb + (size_t)((b*64 + yy)*64)*512;
    for (int it = 0; it < 9; ++it){
      int idx = it*256 + tid;
      if (idx < 2176){
        int xx = idx >> 6, l8 = idx & 63;
        int gx = x0 - 1 + xx;
        bf16x8 v = (bf16x8){0,0,0,0,0,0,0,0};
        if ((unsigned)gx < 64u) v = *(const bf16x8*)(srow + (size_t)gx*512 + l8*8);
        *(bf16x8*)&xbuf[xx*XST + l8*8] = v;
      }
    }
    __syncthreads();
    for (int ks = 0; ks < 48; ++ks){
      int kl = ks*32 + aquad*8;
      int kx = kl >> 9, cc = kl & 511;
      bf16x8 a0 = *(const bf16x8*)&xbuf[(arow + kx)*XST + cc];
      bf16x8 a1 = *(const bf16x8*)&xbuf[(16 + arow + kx)*XST + cc];
      const bf16x8* wp = W8 + ((size_t)((ky*48 + ks)*16 + nh*8 + wave*2))*64 + lane;
#pragma unroll
      for (int t = 0; t < 2; ++t){
        bf16x8 bw = wp[t*64];
        acc[0][t] = MFMA16(a0, bw, acc[0][t]);
        acc[1][t] = MFMA16(a1, bw, acc[1][t]);
      }
    }
  }
#pragma unroll
  for (int t = 0; t < 2; ++t){
    int f = nh*128 + wave*32 + t*16 + arow;
    if (f < 216){
      float bias = omb[f];
#pragma unroll
      for (int s = 0; s < 2; ++s)
#pragma unroll
        for (int r = 0; r < 4; ++r){
          int m = m0 + s*16 + aquad*4 + r;
          om[(size_t)m*216 + f] = acc[s][t][r] + bias;
        }
    }
  }
}

// DCNv2: r6-style staging (params in-register per 4-lane unit), bf16 gather
// from cupb, MFMA GEMM. M-tile 32 (halves weight-frag L2 traffic).
#define VST 776
__global__ __launch_bounds__(256) void k_dcn(const short* __restrict__ cupb,
                                             const float* __restrict__ om,
                                             const short* __restrict__ dwb,
                                             const float* __restrict__ db,
                                             const float* __restrict__ fcal,
                                             float* __restrict__ out){
  __shared__ short valb[32*VST];   // 49664 B
  int m0 = blockIdx.x*32;
  int b = m0 >> 12, y = (m0 & 4095) >> 6, x0 = m0 & 63;
  int tid = threadIdx.x;
  int lane = tid & 63, wave = tid >> 6;
  int unit = tid >> 2, lane4 = tid & 3;    // 64 units x 4 lanes
  int arow = lane & 15, aquad = lane >> 4;
  f32x4 acc[2][4];
#pragma unroll
  for (int s = 0; s < 2; ++s)
#pragma unroll
    for (int t = 0; t < 4; ++t) acc[s][t] = (f32x4){0.f,0.f,0.f,0.f};
  const short* cpb = cupb + (size_t)b*4096*256;
  const bf16x8* W8 = (const bf16x8*)dwb;

  for (int ph = 0; ph < 3; ++ph){
    __syncthreads();
    // 768 samples (32 rows x 8 g x 3 taps); 64 units, 12 iters, 8 ch/lane
    for (int it = 0; it < 12; ++it){
      int u = it*64 + unit;
      int i = u / 24; int r = u - i*24; int g = r / 3; int kk = r - g*3;
      const float* omp = om + (size_t)(m0 + i)*216;
      int k = ph*3 + kk;
      float dy = omp[(g*9 + k)*2 + 0];
      float dx = omp[(g*9 + k)*2 + 1];
      float mv = 1.f / (1.f + expf(-omp[144 + g*9 + k]));
      float yp = (float)(y + ph - 1) + dy;
      float xp = (float)(x0 + i + kk - 1) + dx;
      float yf = floorf(yp), xf = floorf(xp);
      float wy = yp - yf, wx = xp - xf;
      int iy = (int)yf, ix = (int)xf;
      float wA = (1.f-wy)*(1.f-wx), wB = (1.f-wy)*wx, wC = wy*(1.f-wx), wD = wy*wx;
      bool y0ok = (unsigned)iy < 64u, y1ok = (unsigned)(iy+1) < 64u;
      bool x0ok = (unsigned)ix < 64u, x1ok = (unsigned)(ix+1) < 64u;
      if (!(y0ok && x0ok)) wA = 0.f;
      if (!(y0ok && x1ok)) wB = 0.f;
      if (!(y1ok && x0ok)) wC = 0.f;
      if (!(y1ok && x1ok)) wD = 0.f;
      int y0c = min(max(iy, 0), 63), y1c = min(max(iy + 1, 0), 63);
      int x0c = min(max(ix, 0), 63), x1c = min(max(ix + 1, 0), 63);
      int cofs = g*32 + lane4*8;
      bf16x8 l00 = *(const bf16x8*)(cpb + (size_t)(y0c*64 + x0c)*256 + cofs);
      bf16x8 l01 = *(const bf16x8*)(cpb + (size_t)(y0c*64 + x1c)*256 + cofs);
      bf16x8 l10 = *(const bf16x8*)(cpb + (size_t)(y1c*64 + x0c)*256 + cofs);
      bf16x8 l11 = *(const bf16x8*)(cpb + (size_t)(y1c*64 + x1c)*256 + cofs);
      bf16x8 o;
#pragma unroll
      for (int j = 0; j < 8; ++j){
        float v = wA*b2f(l00[j]) + wB*b2f(l01[j]) + wC*b2f(l10[j]) + wD*b2f(l11[j]);
        o[j] = f2b(v * mv);
      }
      *(bf16x8*)&valb[i*VST + kk*256 + g*32 + lane4*8] = o;
    }
    __syncthreads();
    for (int ks = 0; ks < 24; ++ks){
      bf16x8 a0 = *(const bf16x8*)&valb[arow*VST + ks*32 + aquad*8];
      bf16x8 a1 = *(const bf16x8*)&valb[(16 + arow)*VST + ks*32 + aquad*8];
      const bf16x8* wp = W8 + ((size_t)((ph*24 + ks)*16 + wave*4))*64 + lane;
#pragma unroll
      for (int t = 0; t < 4; ++t){
        bf16x8 bw = wp[t*64];
        acc[0][t] = MFMA16(a0, bw, acc[0][t]);
        acc[1][t] = MFMA16(a1, bw, acc[1][t]);
      }
    }
  }
#pragma unroll
  for (int t = 0; t < 4; ++t){
    int f = wave*64 + t*16 + (lane & 15);
    float bias = db[f];
#pragma unroll
    for (int s = 0; s < 2; ++s)
#pragma unroll
      for (int r = 0; r < 4; ++r){
        int m = m0 + s*16 + aquad*4 + r;
        out[(size_t)m*256 + f] = fmaxf(acc[s][t][r] + bias, 0.f) + fcal[(size_t)m*256 + f];
      }
  }
}

extern "C" void kernel_launch(void* const* d_in, const int* in_sizes, int n_in,
                              void* d_out, int out_size, void* d_ws, size_t ws_size,
                              hipStream_t stream){
  const float* fine     = (const float*)d_in[0];
  const float* coarse   = (const float*)d_in[1];
  const float* attend_w = (const float*)d_in[2];
  const float* select_w = (const float*)d_in[3];
  const float* offset_w = (const float*)d_in[4];
  const float* om_w     = (const float*)d_in[5];
  const float* om_b     = (const float*)d_in[6];
  const float* dcn_w    = (const float*)d_in[7];
  const float* dcn_b    = (const float*)d_in[8];
  float* out = (float*)d_out;
  float* ws  = (float*)d_ws;

  float* gate = ws + OFS_GATE;
  float* part = ws + OFS_PART;
  short* cupb = (short*)(ws + OFS_CUPB);
  float* fcal = ws + OFS_FCAL;
  short* algb = (short*)(ws + OFS_ALGB);
  float* om   = ws + OFS_OM;
  short* dwb  = (short*)(ws + OFS_DWB);
  short* omwb = (short*)(ws + OFS_OMWB);
  short* swb  = (short*)(ws + OFS_SWB);
  short* owb  = (short*)(ws + OFS_OWB);

  hipLaunchKernelGGL(k_gap,  dim3(256),  dim3(256), 0, stream, fine, part);
  hipLaunchKernelGGL(k_misc, dim3(5220), dim3(256), 0, stream, part, attend_w, gate,
                     dcn_w, om_w, offset_w, select_w, dwb, omwb, owb, swb, coarse, cupb);
  hipLaunchKernelGGL(k_fa,   dim3(512),  dim3(256), 0, stream, fine, gate, swb, owb,
                     cupb, fcal, algb);
  hipLaunchKernelGGL(k_om,   dim3(1024), dim3(256), 0, stream, algb, omwb, om_b, om);
  hipLaunchKernelGGL(k_dcn,  dim3(512),  dim3(256), 0, stream, cupb, om, dwb, dcn_b, fcal, out);
  (void)in_sizes; (void)n_in; (void)out_size; (void)ws_size;
}